// Round 1
// baseline (637.726 us; speedup 1.0000x reference)
//
#include <hip/hip_runtime.h>
#include <hip/hip_bf16.h>
#include <stdint.h>

// DenseAttention: B=16, S=2048, D=256, fp32 in/out.
// d_out = [output (16*2048*256) | attn_weights (16*2048*2048)] fp32.
// Strategy: bf16 MFMA (16x16x32) for both GEMMs; two-pass softmax in k_attn
// (pass1 rowsums, pass2 normalized weight writes); PV as a separate GEMM
// reading the normalized weights. ws usage ~34 MB (Kb bf16, Vt bf16, maskbits).

#define B_ 16
#define S_ 2048
#define D_ 256
#define SCALE_ 0.0625f

typedef __attribute__((ext_vector_type(8))) short bf16x8;
typedef __attribute__((ext_vector_type(4))) float f32x4;

__device__ __forceinline__ uint16_t f2bf(float f) {
  uint32_t u = __float_as_uint(f);
  u += 0x7fffu + ((u >> 16) & 1u);  // RNE
  return (uint16_t)(u >> 16);
}

// ---------------- K -> bf16 ----------------
__global__ void k_convert(const float* __restrict__ src, uint16_t* __restrict__ dst) {
  const int t = blockIdx.x * blockDim.x + threadIdx.x;  // 8 elems/thread
  const float4* s = (const float4*)src + (size_t)t * 2;
  float4 a = s[0], b = s[1];
  ushort4 lo = { f2bf(a.x), f2bf(a.y), f2bf(a.z), f2bf(a.w) };
  ushort4 hi = { f2bf(b.x), f2bf(b.y), f2bf(b.z), f2bf(b.w) };
  ((ushort4*)dst)[(size_t)t * 2]     = lo;
  ((ushort4*)dst)[(size_t)t * 2 + 1] = hi;
}

// ---------------- V -> V^T bf16 ----------------
__global__ void k_transpose(const float* __restrict__ V, uint16_t* __restrict__ Vt) {
  __shared__ float tile[64][68];
  const int b = blockIdx.z, kv0 = blockIdx.x * 64, d0 = blockIdx.y * 64;
  const int t = threadIdx.x;
  {
    const int r = t >> 2, c = (t & 3) * 16;
    const float4* src = (const float4*)(V + ((size_t)b * S_ + kv0 + r) * D_ + d0 + c);
    float4 x0 = src[0], x1 = src[1], x2 = src[2], x3 = src[3];
    *(float4*)&tile[r][c]      = x0;
    *(float4*)&tile[r][c + 4]  = x1;
    *(float4*)&tile[r][c + 8]  = x2;
    *(float4*)&tile[r][c + 12] = x3;
  }
  __syncthreads();
  {
    const int dl = t >> 2, c = (t & 3) * 16;
    uint16_t o[16];
#pragma unroll
    for (int i = 0; i < 16; ++i) o[i] = f2bf(tile[c + i][dl]);
    uint16_t* dst = Vt + ((size_t)b * D_ + d0 + dl) * S_ + kv0 + c;
#pragma unroll
    for (int i = 0; i < 4; ++i) {
      ushort4 v4 = { o[4*i], o[4*i+1], o[4*i+2], o[4*i+3] };
      *(ushort4*)(dst + 4*i) = v4;
    }
  }
}

// ---------------- mask -> bit-packed u64 per (row, 64-kv chunk) ----------------
__global__ void k_maskpack(const int* __restrict__ mask, unsigned long long* __restrict__ Mb) {
  const int wid  = blockIdx.x * 4 + (threadIdx.x >> 6);
  const int lane = threadIdx.x & 63;
  const int row = wid >> 5, w64 = wid & 31;
  const int m = mask[(size_t)row * S_ + w64 * 64 + lane];
  unsigned long long bits = __ballot(m != 0);
  if (lane == 0) Mb[row * 32 + w64] = bits;
}

// ---------------- scores + softmax (two-pass), writes normalized weights ----------------
__global__ __launch_bounds__(512, 2) void k_attn(
    const float* __restrict__ Q, const uint16_t* __restrict__ Kb,
    const unsigned long long* __restrict__ Mb, float* __restrict__ attn) {
  __shared__ uint16_t Ks[128 * 256];  // 64 KB, 16B-granule XOR-swizzled [kv][d]
  const int b = blockIdx.y, q0 = blockIdx.x * 128;
  const int tid = threadIdx.x, w = tid >> 6, lane = tid & 63;
  const int wq = w >> 1, wkv = w & 1;
  const int l15 = lane & 15, lq = lane >> 4;
  const int qbase = q0 + wq * 32;

  // Q fragments in VGPRs: 2 q-subtiles x 8 d-chunks
  bf16x8 aq[2][8];
#pragma unroll
  for (int qt = 0; qt < 2; ++qt) {
    const float* qrow = Q + ((size_t)b * S_ + qbase + qt * 16 + l15) * D_;
#pragma unroll
    for (int dc = 0; dc < 8; ++dc) {
      const float4* p = (const float4*)(qrow + dc * 32 + lq * 8);
      float4 x = p[0], y = p[1];
      union { bf16x8 v; uint16_t u[8]; } fr;
      fr.u[0] = f2bf(x.x); fr.u[1] = f2bf(x.y); fr.u[2] = f2bf(x.z); fr.u[3] = f2bf(x.w);
      fr.u[4] = f2bf(y.x); fr.u[5] = f2bf(y.y); fr.u[6] = f2bf(y.z); fr.u[7] = f2bf(y.w);
      aq[qt][dc] = fr.v;
    }
  }

  float rowpart[2][4] = {{0.f,0.f,0.f,0.f},{0.f,0.f,0.f,0.f}};
  float inv_[2][4];

  for (int pass = 0; pass < 2; ++pass) {
    for (int kvt = 0; kvt < 16; ++kvt) {
      const int kvb = kvt * 128;
      // stage K tile (128 kv x 256 d bf16), swizzle low-3 granule bits by row
      {
        const uint4* src = (const uint4*)(Kb + ((size_t)b * S_ + kvb) * D_);
#pragma unroll
        for (int i = 0; i < 8; ++i) {
          const int g = i * 512 + tid;
          const int row = g >> 5, gcol = g & 31;
          uint4 val = src[row * 32 + gcol];
          const int gs = (gcol & ~7) | ((gcol ^ row) & 7);
          *(uint4*)&Ks[(row * 32 + gs) * 8] = val;
        }
      }
      __syncthreads();

      f32x4 acc[2][4];
#pragma unroll
      for (int qt = 0; qt < 2; ++qt)
#pragma unroll
        for (int kt = 0; kt < 4; ++kt) acc[qt][kt] = 0.f;

#pragma unroll
      for (int dc = 0; dc < 8; ++dc) {
        bf16x8 bk[4];
#pragma unroll
        for (int kt = 0; kt < 4; ++kt) {
          const int kvl = wkv * 64 + kt * 16 + l15;
          const int g = dc * 4 + lq;
          const int gs = (g & ~7) | ((g ^ kvl) & 7);
          bk[kt] = *(const bf16x8*)&Ks[(kvl * 32 + gs) * 8];
        }
#pragma unroll
        for (int qt = 0; qt < 2; ++qt)
#pragma unroll
          for (int kt = 0; kt < 4; ++kt)
            acc[qt][kt] = __builtin_amdgcn_mfma_f32_16x16x32_bf16(
                aq[qt][dc], bk[kt], acc[qt][kt], 0, 0, 0);
      }

      // epilogue: exp + mask; pass0 accumulates rowsums, pass1 stores weights
#pragma unroll
      for (int qt = 0; qt < 2; ++qt) {
#pragma unroll
        for (int r = 0; r < 4; ++r) {
          const int row = qbase + qt * 16 + lq * 4 + r;
          const unsigned long long mw = Mb[row * 32 + kvt * 2 + wkv];
#pragma unroll
          for (int kt = 0; kt < 4; ++kt) {
            const float s = acc[qt][kt][r] * SCALE_;
            const int bit = kt * 16 + l15;
            const float e = ((mw >> bit) & 1ull) ? __expf(s) : 0.0f;
            if (pass == 0) {
              rowpart[qt][r] += e;
            } else {
              attn[(size_t)b * S_ * S_ + (size_t)row * S_ +
                   kvb + wkv * 64 + kt * 16 + l15] = e * inv_[qt][r];
            }
          }
        }
      }
      __syncthreads();
    }

    if (pass == 0) {
      // reduce over the 16 lanes sharing each row
#pragma unroll
      for (int qt = 0; qt < 2; ++qt)
#pragma unroll
        for (int r = 0; r < 4; ++r) {
          float v = rowpart[qt][r];
          v += __shfl_xor(v, 1); v += __shfl_xor(v, 2);
          v += __shfl_xor(v, 4); v += __shfl_xor(v, 8);
          rowpart[qt][r] = v;
        }
      // combine the two kv-half waves via LDS (reuse Ks area)
      float* red = (float*)(void*)Ks;
      if (l15 == 0) {
#pragma unroll
        for (int qt = 0; qt < 2; ++qt)
#pragma unroll
          for (int r = 0; r < 4; ++r) {
            const int rl = wq * 32 + qt * 16 + lq * 4 + r;
            red[wkv * 128 + rl] = rowpart[qt][r];
          }
      }
      __syncthreads();
#pragma unroll
      for (int qt = 0; qt < 2; ++qt)
#pragma unroll
        for (int r = 0; r < 4; ++r) {
          const int rl = wq * 32 + qt * 16 + lq * 4 + r;
          inv_[qt][r] = 1.0f / (red[rl] + red[128 + rl]);
        }
      __syncthreads();
    }
  }
}

// ---------------- O = attn @ V  (attn fp32 -> bf16 on stage, Vt pre-transposed) ----------------
__global__ __launch_bounds__(512, 2) void k_out(
    const float* __restrict__ attn, const uint16_t* __restrict__ Vt,
    float* __restrict__ O) {
  __shared__ uint16_t As[128 * 64];  // 16 KB swizzled [q][kv]
  __shared__ uint16_t Vs[256 * 64];  // 32 KB swizzled [d][kv]
  const int b = blockIdx.y, q0 = blockIdx.x * 128;
  const int tid = threadIdx.x, w = tid >> 6, lane = tid & 63;
  const int wq = w >> 2, wd = w & 3;  // wave: 64q x 64d
  const int l15 = lane & 15, lq = lane >> 4;

  f32x4 acc[4][4];
#pragma unroll
  for (int qt = 0; qt < 4; ++qt)
#pragma unroll
    for (int dt = 0; dt < 4; ++dt) acc[qt][dt] = 0.f;

  for (int kvt = 0; kvt < 32; ++kvt) {
    const int kvb = kvt * 64;
    // stage attn tile: 128 q x 64 kv, convert to bf16
    {
      const int row = tid >> 2, gc = (tid & 3) * 2;
      const float4* ap = (const float4*)(attn + ((size_t)b * S_ + q0 + row) * S_ + kvb + (tid & 3) * 16);
      float4 a0 = ap[0], a1 = ap[1], a2 = ap[2], a3 = ap[3];
      union { uint4 u; uint16_t s[8]; } g0, g1;
      g0.s[0] = f2bf(a0.x); g0.s[1] = f2bf(a0.y); g0.s[2] = f2bf(a0.z); g0.s[3] = f2bf(a0.w);
      g0.s[4] = f2bf(a1.x); g0.s[5] = f2bf(a1.y); g0.s[6] = f2bf(a1.z); g0.s[7] = f2bf(a1.w);
      g1.s[0] = f2bf(a2.x); g1.s[1] = f2bf(a2.y); g1.s[2] = f2bf(a2.z); g1.s[3] = f2bf(a2.w);
      g1.s[4] = f2bf(a3.x); g1.s[5] = f2bf(a3.y); g1.s[6] = f2bf(a3.z); g1.s[7] = f2bf(a3.w);
      *(uint4*)&As[(row * 8 + (gc ^ (row & 7))) * 8]       = g0.u;
      *(uint4*)&As[(row * 8 + ((gc + 1) ^ (row & 7))) * 8] = g1.u;
    }
    // stage V^T tile: 256 d x 64 kv (already bf16)
    {
      const int d = tid >> 1, gc = (tid & 1) * 4;
      const uint4* vp = (const uint4*)(Vt + ((size_t)b * D_ + d) * S_ + kvb + (tid & 1) * 32);
#pragma unroll
      for (int i = 0; i < 4; ++i) {
        uint4 vv = vp[i];
        *(uint4*)&Vs[(d * 8 + ((gc + i) ^ (d & 7))) * 8] = vv;
      }
    }
    __syncthreads();

#pragma unroll
    for (int kc = 0; kc < 2; ++kc) {
      bf16x8 af[4], bv[4];
      const int g = kc * 4 + lq;
#pragma unroll
      for (int qt = 0; qt < 4; ++qt) {
        const int ql = wq * 64 + qt * 16 + l15;
        af[qt] = *(const bf16x8*)&As[(ql * 8 + (g ^ (ql & 7))) * 8];
      }
#pragma unroll
      for (int dt = 0; dt < 4; ++dt) {
        const int dl = wd * 64 + dt * 16 + l15;
        bv[dt] = *(const bf16x8*)&Vs[(dl * 8 + (g ^ (dl & 7))) * 8];
      }
#pragma unroll
      for (int qt = 0; qt < 4; ++qt)
#pragma unroll
        for (int dt = 0; dt < 4; ++dt)
          acc[qt][dt] = __builtin_amdgcn_mfma_f32_16x16x32_bf16(af[qt], bv[dt], acc[qt][dt], 0, 0, 0);
    }
    __syncthreads();
  }

#pragma unroll
  for (int qt = 0; qt < 4; ++qt)
#pragma unroll
    for (int dt = 0; dt < 4; ++dt)
#pragma unroll
      for (int r = 0; r < 4; ++r)
        O[((size_t)b * S_ + q0 + wq * 64 + qt * 16 + lq * 4 + r) * D_ +
          wd * 64 + dt * 16 + l15] = acc[qt][dt][r];
}

extern "C" void kernel_launch(void* const* d_in, const int* in_sizes, int n_in,
                              void* d_out, int out_size, void* d_ws, size_t ws_size,
                              hipStream_t stream) {
  const float* q = (const float*)d_in[0];
  const float* k = (const float*)d_in[1];
  const float* v = (const float*)d_in[2];
  const int* mask = (const int*)d_in[3];

  float* out  = (float*)d_out;
  float* attn = out + (size_t)B_ * S_ * D_;

  uint16_t* Kb = (uint16_t*)d_ws;                                   // 16.78 MB
  uint16_t* Vt = Kb + (size_t)B_ * S_ * D_;                         // 16.78 MB
  unsigned long long* Mb = (unsigned long long*)(Vt + (size_t)B_ * S_ * D_);  // 0.5 MB
  // total ws: ~34 MB

  k_convert<<<dim3(2048), dim3(512), 0, stream>>>(k, Kb);
  k_transpose<<<dim3(32, 4, 16), dim3(256), 0, stream>>>(v, Vt);
  k_maskpack<<<dim3(16384), dim3(256), 0, stream>>>(mask, Mb);
  k_attn<<<dim3(16, 16), dim3(512), 0, stream>>>(q, Kb, Mb, attn);
  k_out<<<dim3(16, 16), dim3(512), 0, stream>>>(attn, Vt, out);
}